// Round 7
// baseline (283.415 us; speedup 1.0000x reference)
//
#include <hip/hip_runtime.h>
#include <stdint.h>

#define D_MODEL 1024
#define NUM_HEADS 16
#define DK 64
#define SEQ 2048
#define BATCH 2
#define MROWS (BATCH * SEQ) /* 4096 */
#define LOG2E 1.4426950408889634f
#define FIXM 14.0f /* static softmax max, base-2 domain */

typedef short bf16x8 __attribute__((ext_vector_type(8)));
typedef float f32x4 __attribute__((ext_vector_type(4)));

__device__ __forceinline__ unsigned short f2bf(float f) { // RNE
    unsigned int u = __float_as_uint(f);
    u = (u + 0x7fffu + ((u >> 16) & 1u)) >> 16;
    return (unsigned short)u;
}
__device__ __forceinline__ unsigned short f2bf_trunc(float f) { // 1-op, P only
    return (unsigned short)(__float_as_uint(f) >> 16);
}
__device__ __forceinline__ float bf2f(unsigned short h) {
    return __uint_as_float(((unsigned int)h) << 16);
}
__device__ __forceinline__ void async16(const void* g, void* l) {
    __builtin_amdgcn_global_load_lds(
        (const __attribute__((address_space(1))) void*)g,
        (__attribute__((address_space(3))) void*)l, 16, 0, 0);
}
// 64-col bf16 tile: 8 16B-chunks/row; phys chunk p of row r holds logical p^(r&7)
#define SWZ64(row, b) ((((row) * 8) + ((b) ^ ((row) & 7))) * 8)

// ---------------- merged cast fp32 -> bf16 ----------------
__global__ void cast_all(const float4* __restrict__ X, const float4* __restrict__ Wq,
                         const float4* __restrict__ Wk, const float4* __restrict__ Wv,
                         const float4* __restrict__ Wo, ushort4* __restrict__ Xb,
                         ushort4* __restrict__ Wqkvb, ushort4* __restrict__ Wob) {
    int i = blockIdx.x * blockDim.x + threadIdx.x;
    const float4* src;
    ushort4* dst;
    int off;
    if (i < 1048576) { src = X; dst = Xb; off = i; }
    else if (i < 1310720) { src = Wq; dst = Wqkvb; off = i - 1048576; }
    else if (i < 1572864) { src = Wk; dst = Wqkvb + 262144; off = i - 1310720; }
    else if (i < 1835008) { src = Wv; dst = Wqkvb + 524288; off = i - 1572864; }
    else { src = Wo; dst = Wob; off = i - 1835008; }
    float4 v = src[off];
    ushort4 o;
    o.x = f2bf(v.x); o.y = f2bf(v.y); o.z = f2bf(v.z); o.w = f2bf(v.w);
    dst[off] = o;
}

// ---------------- GEMM 128 x TN, BK=64: C = A * B^T ----------------
template <int TN, int OUT_BF16>
__global__ __launch_bounds__(256) void gemm_tile(
    const unsigned short* __restrict__ A, const unsigned short* __restrict__ B,
    void* __restrict__ Cout, int M, int N, int K) {
    __shared__ unsigned short As[128 * 64];
    __shared__ unsigned short Bs[TN * 64];
    const int m0 = blockIdx.y * 128, n0 = blockIdx.x * TN;
    const int t = threadIdx.x;
    const int lane = t & 63, wave = t >> 6;
    const int mA = lane & 15, quad = lane >> 4;
    constexpr int MI = (TN == 128) ? 4 : 2;
    constexpr int NI = 4;
    const int wr = (TN == 128) ? (wave >> 1) * 64 : wave * 32;
    const int wc = (TN == 128) ? (wave & 1) * 64 : 0;

    f32x4 acc[MI][NI] = {};
    for (int k0 = 0; k0 < K; k0 += 64) {
#pragma unroll
        for (int i = 0; i < 4; ++i) {
            int ch = i * 256 + t;
            int r = ch >> 3, b = (ch & 7) ^ (r & 7);
            async16(A + (size_t)(m0 + r) * K + k0 + b * 8, (char*)As + ch * 16);
        }
#pragma unroll
        for (int i = 0; i < TN / 32; ++i) {
            int ch = i * 256 + t;
            int r = ch >> 3, b = (ch & 7) ^ (r & 7);
            async16(B + (size_t)(n0 + r) * K + k0 + b * 8, (char*)Bs + ch * 16);
        }
        __syncthreads();
#pragma unroll
        for (int kk = 0; kk < 2; ++kk) {
            bf16x8 af[MI], bfr[NI];
#pragma unroll
            for (int mi = 0; mi < MI; ++mi) {
                int rr = wr + mi * 16 + mA;
                af[mi] = *(const bf16x8*)&As[SWZ64(rr, kk * 4 + quad)];
            }
#pragma unroll
            for (int ni = 0; ni < NI; ++ni) {
                int rr = wc + ni * 16 + mA;
                bfr[ni] = *(const bf16x8*)&Bs[SWZ64(rr, kk * 4 + quad)];
            }
#pragma unroll
            for (int mi = 0; mi < MI; ++mi)
#pragma unroll
                for (int ni = 0; ni < NI; ++ni)
                    acc[mi][ni] = __builtin_amdgcn_mfma_f32_16x16x32_bf16(
                        af[mi], bfr[ni], acc[mi][ni], 0, 0, 0);
        }
        __syncthreads();
    }
#pragma unroll
    for (int mi = 0; mi < MI; ++mi)
#pragma unroll
        for (int ni = 0; ni < NI; ++ni)
#pragma unroll
            for (int r = 0; r < 4; ++r) {
                int gm = m0 + wr + mi * 16 + quad * 4 + r;
                int gn = n0 + wc + ni * 16 + mA;
                if (OUT_BF16)
                    ((unsigned short*)Cout)[(size_t)gm * N + gn] = f2bf(acc[mi][ni][r]);
                else
                    ((float*)Cout)[(size_t)gm * N + gn] = acc[mi][ni][r];
            }
}

// ---------------- merged RoPE Q/K + V transpose (tile-local Vtt) ----------
// bx < 4096: rope (4 elems/thread). bx >= 4096: vtrans 64x64 tile into
// Vtt[bh][jt][d][j_local] (each 64-j tile is a contiguous 8 KB [d][j] block).
__global__ __launch_bounds__(256) void rope_vt(const unsigned short* __restrict__ QKV,
                                               unsigned short* __restrict__ Qr,
                                               unsigned short* __restrict__ Kr,
                                               unsigned short* __restrict__ Vtt) {
    __shared__ unsigned short T[64][80];
    const int bx = blockIdx.x;
    const int t = threadIdx.x;
    if (bx < 4096) { // ---- RoPE ----
        int tid = bx * 256 + t;
        int bs = tid >> 8;
        int p4 = tid & 255;
        int b = bs >> 11, spos = bs & 2047;
        int h = p4 >> 4, dd = (p4 & 15) * 4;
        float sn0, cs0, sn1, cs1;
        {
            float if0 = __expf(-(float)dd * (9.210340371976184f / 64.0f));
            float if1 = __expf(-(float)(dd + 2) * (9.210340371976184f / 64.0f));
            __sincosf((float)spos * if0, &sn0, &cs0);
            __sincosf((float)spos * if1, &sn1, &cs1);
        }
        size_t src = (size_t)bs * 3072 + h * 64 + dd;
        ushort4 qw = *(const ushort4*)&QKV[src];
        ushort4 kw = *(const ushort4*)&QKV[src + 1024];
        ushort4 qo_, ko_;
        float e = bf2f(qw.x), o = bf2f(qw.y);
        qo_.x = f2bf(e * cs0 - o * sn0); qo_.y = f2bf(o * cs0 + e * sn0);
        e = bf2f(qw.z); o = bf2f(qw.w);
        qo_.z = f2bf(e * cs1 - o * sn1); qo_.w = f2bf(o * cs1 + e * sn1);
        e = bf2f(kw.x); o = bf2f(kw.y);
        ko_.x = f2bf(e * cs0 - o * sn0); ko_.y = f2bf(o * cs0 + e * sn0);
        e = bf2f(kw.z); o = bf2f(kw.w);
        ko_.z = f2bf(e * cs1 - o * sn1); ko_.w = f2bf(o * cs1 + e * sn1);
        size_t qb = (((size_t)(b * NUM_HEADS + h) * SEQ + spos) * DK + dd);
        *(ushort4*)&Qr[qb] = qo_;
        *(ushort4*)&Kr[qb] = ko_;
    } else { // ---- V transpose into tile-local layout ----
        int idx = bx - 4096;
        const int s0 = (idx & 31) * 64, bh = idx >> 5;
        const int b = bh >> 4, h = bh & 15;
#pragma unroll
        for (int i = 0; i < 2; ++i) {
            int ch = i * 256 + t;
            int row = ch >> 3, bc = ch & 7;
            *(int4*)&T[row][bc * 8] =
                *(const int4*)&QKV[(size_t)(b * SEQ + s0 + row) * 3072 + 2048 + h * 64 + bc * 8];
        }
        __syncthreads();
        const size_t obase = (size_t)bh * DK * SEQ + (size_t)s0 * DK; // 8 KB tile
#pragma unroll
        for (int i = 0; i < 2; ++i) {
            int ch = i * 256 + t;
            int d = ch >> 3, sb = ch & 7;
            unsigned short tmp[8];
#pragma unroll
            for (int j = 0; j < 8; ++j) tmp[j] = T[sb * 8 + j][d];
            *(int4*)&Vtt[obase + (size_t)d * 64 + sb * 8] = *(int4*)tmp;
        }
    }
}

// ---------------- Flash attention v7: barrier-free, L2-direct K/V ----------
// 256 thr / 4 waves; block = 64 q rows of one (b,h). K/V fragments loaded
// DIRECTLY from global (L2-resident: 512 KB per bh); no LDS staging, no
// __syncthreads anywhere. P roundtrip in per-wave swizzled LDS. Static-max
// softmax. Flat grid 1024 with XCD swizzle: xcd = id&7 owns bh in
// [xcd*4, xcd*4+4) (2 MB KV working set per XCD L2), LPT on qt.
__global__ __launch_bounds__(256, 4) void flash_attn7(
    const unsigned short* __restrict__ Qr, const unsigned short* __restrict__ Kr,
    const unsigned short* __restrict__ Vtt, unsigned short* __restrict__ Att) {
    __shared__ unsigned short Ps[4][16 * 64]; // 8 KB, XOR-swizzled rows
    const int id = blockIdx.x;
    const int xcd = id & 7, within = id >> 3;
    const int bh = xcd * 4 + (within & 3);
    const int qt = 31 - (within >> 2); // LPT: longest first
    const int t = threadIdx.x;
    const int lane = t & 63, wave = t >> 6;
    const int mA = lane & 15, quad = lane >> 4;
    const int qr0 = qt * 64 + wave * 16;
    const size_t qkbase = (size_t)bh * SEQ * DK;
    const unsigned short* Kg = Kr + qkbase;
    const unsigned short* Vg = Vtt + qkbase; // tile-local [jt][d][64]

    // Q fragments pre-scaled by 1/sqrt(dk)*log2e (base-2 softmax domain)
    bf16x8 aq[2];
#pragma unroll
    for (int c = 0; c < 2; ++c) {
        bf16x8 raw = *(const bf16x8*)&Qr[qkbase + (size_t)(qr0 + mA) * DK + c * 32 + quad * 8];
        bf16x8 s;
#pragma unroll
        for (int j = 0; j < 8; ++j)
            s[j] = (short)f2bf(bf2f((unsigned short)raw[j]) * (0.125f * LOG2E));
        aq[c] = s;
    }

    f32x4 accT[4] = {}; // O^T tiles: C-layout col = q_local, row = outdim_local
    float lsum[4] = {};
    unsigned short* Pw = Ps[wave];

    for (int jt = 0; jt <= qt; ++jt) {
        const int j0 = jt * 64;
        // ---- K & V fragments straight from global (L2). 16 b128 loads, all
        // independent -> deep MLP; compiler interleaves via vmcnt. ----
        bf16x8 kf[4][2], vf[4][2];
#pragma unroll
        for (int js = 0; js < 4; ++js)
#pragma unroll
            for (int c = 0; c < 2; ++c)
                kf[js][c] = *(const bf16x8*)&Kg[(size_t)(j0 + js * 16 + mA) * DK + c * 32 + quad * 8];
#pragma unroll
        for (int tn = 0; tn < 4; ++tn)
#pragma unroll
            for (int c = 0; c < 2; ++c)
                vf[tn][c] = *(const bf16x8*)&Vg[(size_t)jt * 4096 + (tn * 16 + mA) * 64 + c * 32 + quad * 8];

        // ---- QK^T: 16x64 scores (base-2 domain) ----
        f32x4 sc[4] = {};
#pragma unroll
        for (int js = 0; js < 4; ++js) {
            sc[js] = __builtin_amdgcn_mfma_f32_16x16x32_bf16(aq[0], kf[js][0], sc[js], 0, 0, 0);
            sc[js] = __builtin_amdgcn_mfma_f32_16x16x32_bf16(aq[1], kf[js][1], sc[js], 0, 0, 0);
        }
        if (jt == qt) { // diagonal causal mask
#pragma unroll
            for (int js = 0; js < 4; ++js) {
                int gcol = j0 + js * 16 + mA;
#pragma unroll
                for (int r = 0; r < 4; ++r)
                    if (gcol > qr0 + quad * 4 + r) sc[js][r] = -1e30f;
            }
        }

        // ---- p = exp2(s - FIXM); P via per-wave swizzled LDS (no barrier) --
#pragma unroll
        for (int js = 0; js < 4; ++js)
#pragma unroll
            for (int r = 0; r < 4; ++r) {
                float p = __builtin_amdgcn_exp2f(sc[js][r] - FIXM);
                lsum[r] += p;
                int q = quad * 4 + r;
                Pw[SWZ64(q, js * 2 + (mA >> 3)) + (mA & 7)] = f2bf_trunc(p);
            }
        bf16x8 ap0 = *(const bf16x8*)&Pw[SWZ64(mA, quad)];
        bf16x8 ap1 = *(const bf16x8*)&Pw[SWZ64(mA, quad + 4)];
#pragma unroll
        for (int tn = 0; tn < 4; ++tn) { // A=V, B=P -> O^T
            accT[tn] = __builtin_amdgcn_mfma_f32_16x16x32_bf16(vf[tn][0], ap0, accT[tn], 0, 0, 0);
            accT[tn] = __builtin_amdgcn_mfma_f32_16x16x32_bf16(vf[tn][1], ap1, accT[tn], 0, 0, 0);
        }
    }

    // ---- epilogue: row-sum reduce + broadcast, all in-register ----
#pragma unroll
    for (int r = 0; r < 4; ++r)
#pragma unroll
        for (int off = 1; off < 16; off <<= 1)
            lsum[r] += __shfl_xor(lsum[r], off, 64);
    // lane needs sum for q-row = mA (rows quad*4+r live in quad mA>>2)
    const int srcl = (mA >> 2) << 4;
    float s0 = __shfl(lsum[0], srcl), s1 = __shfl(lsum[1], srcl);
    float s2 = __shfl(lsum[2], srcl), s3 = __shfl(lsum[3], srcl);
    const int rr = mA & 3;
    float sum = (rr == 0) ? s0 : (rr == 1) ? s1 : (rr == 2) ? s2 : s3;
    const float rl = 1.0f / sum;

    const int b = bh >> 4, h = bh & 15;
#pragma unroll
    for (int tn = 0; tn < 4; ++tn) {
        ushort4 o;
        o.x = f2bf(accT[tn][0] * rl);
        o.y = f2bf(accT[tn][1] * rl);
        o.z = f2bf(accT[tn][2] * rl);
        o.w = f2bf(accT[tn][3] * rl);
        *(ushort4*)&Att[(size_t)(b * SEQ + qr0 + mA) * D_MODEL + h * DK + tn * 16 + quad * 4] = o;
    }
}

extern "C" void kernel_launch(void* const* d_in, const int* in_sizes, int n_in,
                              void* d_out, int out_size, void* d_ws, size_t ws_size,
                              hipStream_t stream) {
    const float* X = (const float*)d_in[0];
    const float* Wq = (const float*)d_in[1];
    const float* Wk = (const float*)d_in[2];
    const float* Wv = (const float*)d_in[3];
    const float* Wo = (const float*)d_in[4];

    char* ws = (char*)d_ws;
    unsigned short* Xb     = (unsigned short*)(ws + 0);
    unsigned short* Wqkvb  = (unsigned short*)(ws + (8u << 20));
    unsigned short* Wob    = (unsigned short*)(ws + (14u << 20));
    unsigned short* QKVraw = (unsigned short*)(ws + (16u << 20));
    unsigned short* Kr     = (unsigned short*)(ws + (40u << 20));
    unsigned short* Vtt    = (unsigned short*)(ws + (48u << 20));
    unsigned short* Qr     = Xb;     // alias: Xb dead after QKV GEMM
    unsigned short* Att    = QKVraw; // alias: QKVraw dead after rope_vt

    cast_all<<<8192, 256, 0, stream>>>((const float4*)X, (const float4*)Wq,
                                       (const float4*)Wk, (const float4*)Wv,
                                       (const float4*)Wo, (ushort4*)Xb,
                                       (ushort4*)Wqkvb, (ushort4*)Wob);

    // fused QKV projection: [4096 x 1024] x [3072 x 1024]^T
    gemm_tile<128, 1><<<dim3(3072 / 128, MROWS / 128), 256, 0, stream>>>(
        Xb, Wqkvb, QKVraw, MROWS, 3072, D_MODEL);

    rope_vt<<<4096 + 1024, 256, 0, stream>>>(QKVraw, Qr, Kr, Vtt);

    flash_attn7<<<1024, 256, 0, stream>>>(Qr, Kr, Vtt, Att);

    // output projection (fp32 out), 128x64 tiles for 2 blocks/CU
    gemm_tile<64, 0><<<dim3(D_MODEL / 64, MROWS / 128), 256, 0, stream>>>(
        Att, Wob, d_out, MROWS, D_MODEL, D_MODEL);
}

// Round 8
// 182.614 us; speedup vs baseline: 1.5520x; 1.5520x over previous
//
#include <hip/hip_runtime.h>
#include <stdint.h>

#define D_MODEL 1024
#define NUM_HEADS 16
#define DK 64
#define SEQ 2048
#define BATCH 2
#define MROWS (BATCH * SEQ) /* 4096 */
#define LOG2E 1.4426950408889634f
#define FIXM 14.0f /* static softmax max, base-2 domain */

typedef short bf16x8 __attribute__((ext_vector_type(8)));
typedef float f32x4 __attribute__((ext_vector_type(4)));

__device__ __forceinline__ unsigned short f2bf(float f) { // RNE
    unsigned int u = __float_as_uint(f);
    u = (u + 0x7fffu + ((u >> 16) & 1u)) >> 16;
    return (unsigned short)u;
}
__device__ __forceinline__ unsigned short f2bf_trunc(float f) { // 1-op, P only
    return (unsigned short)(__float_as_uint(f) >> 16);
}
__device__ __forceinline__ float bf2f(unsigned short h) {
    return __uint_as_float(((unsigned int)h) << 16);
}
__device__ __forceinline__ void async16(const void* g, void* l) {
    __builtin_amdgcn_global_load_lds(
        (const __attribute__((address_space(1))) void*)g,
        (__attribute__((address_space(3))) void*)l, 16, 0, 0);
}
// 64-col bf16 tile: 8 16B-chunks/row; phys chunk p of row r holds logical p^(r&7)
#define SWZ64(row, b) ((((row) * 8) + ((b) ^ ((row) & 7))) * 8)

// ---------------- merged cast fp32 -> bf16 ----------------
__global__ void cast_all(const float4* __restrict__ X, const float4* __restrict__ Wq,
                         const float4* __restrict__ Wk, const float4* __restrict__ Wv,
                         const float4* __restrict__ Wo, ushort4* __restrict__ Xb,
                         ushort4* __restrict__ Wqkvb, ushort4* __restrict__ Wob) {
    int i = blockIdx.x * blockDim.x + threadIdx.x;
    const float4* src;
    ushort4* dst;
    int off;
    if (i < 1048576) { src = X; dst = Xb; off = i; }
    else if (i < 1310720) { src = Wq; dst = Wqkvb; off = i - 1048576; }
    else if (i < 1572864) { src = Wk; dst = Wqkvb + 262144; off = i - 1310720; }
    else if (i < 1835008) { src = Wv; dst = Wqkvb + 524288; off = i - 1572864; }
    else { src = Wo; dst = Wob; off = i - 1835008; }
    float4 v = src[off];
    ushort4 o;
    o.x = f2bf(v.x); o.y = f2bf(v.y); o.z = f2bf(v.z); o.w = f2bf(v.w);
    dst[off] = o;
}

// ---------------- QKV GEMM 128x128 BK=64 + fused RoPE / V-transpose --------
// C = X * Wqkv^T (M=4096, N=3072, K=1024). Epilogue routes by n-section:
// sec 0 (Q) / 1 (K): apply RoPE in-register (partner value via shfl_xor(1),
// adjacent d = adjacent lane) and store to Qr/Kr [bh][s][dk].
// sec 2 (V): store to Vt [bh][d][s] -- C-layout rows are 4 consecutive s at
// fixed d, so each (mi,ni) tile is one b64 store. QKVraw never materialized.
__global__ __launch_bounds__(256) void gemm_qkv_rope(
    const unsigned short* __restrict__ A, const unsigned short* __restrict__ B,
    unsigned short* __restrict__ Qr, unsigned short* __restrict__ Kr,
    unsigned short* __restrict__ Vt) {
    __shared__ unsigned short As[128 * 64];
    __shared__ unsigned short Bs[128 * 64];
    const int K = D_MODEL, N = 3072;
    const int m0 = blockIdx.y * 128, n0 = blockIdx.x * 128;
    const int t = threadIdx.x;
    const int lane = t & 63, wave = t >> 6;
    const int mA = lane & 15, quad = lane >> 4;
    const int wr = (wave >> 1) * 64, wc = (wave & 1) * 64;

    f32x4 acc[4][4] = {};
    for (int k0 = 0; k0 < K; k0 += 64) {
#pragma unroll
        for (int i = 0; i < 4; ++i) {
            int ch = i * 256 + t;
            int r = ch >> 3, b = (ch & 7) ^ (r & 7);
            async16(A + (size_t)(m0 + r) * K + k0 + b * 8, (char*)As + ch * 16);
            async16(B + (size_t)(n0 + r) * K + k0 + b * 8, (char*)Bs + ch * 16);
        }
        __syncthreads();
#pragma unroll
        for (int kk = 0; kk < 2; ++kk) {
            bf16x8 af[4], bfr[4];
#pragma unroll
            for (int mi = 0; mi < 4; ++mi) {
                int rr = wr + mi * 16 + mA;
                af[mi] = *(const bf16x8*)&As[SWZ64(rr, kk * 4 + quad)];
            }
#pragma unroll
            for (int ni = 0; ni < 4; ++ni) {
                int rr = wc + ni * 16 + mA;
                bfr[ni] = *(const bf16x8*)&Bs[SWZ64(rr, kk * 4 + quad)];
            }
#pragma unroll
            for (int mi = 0; mi < 4; ++mi)
#pragma unroll
                for (int ni = 0; ni < 4; ++ni)
                    acc[mi][ni] = __builtin_amdgcn_mfma_f32_16x16x32_bf16(
                        af[mi], bfr[ni], acc[mi][ni], 0, 0, 0);
        }
        __syncthreads();
    }

    const int sec = n0 >> 10; // block-uniform: 0=Q, 1=K, 2=V
    if (sec == 2) { // ---- V: direct transposed store ----
#pragma unroll
        for (int mi = 0; mi < 4; ++mi)
#pragma unroll
            for (int ni = 0; ni < 4; ++ni) {
                int gm = m0 + wr + mi * 16 + quad * 4; // 4 consecutive s rows
                int gn = n0 + wc + ni * 16 + mA;
                int d = gn & 1023, h = d >> 6, dk = d & 63;
                int b = gm >> 11, s = gm & 2047;
                ushort4 o;
                o.x = f2bf(acc[mi][ni][0]);
                o.y = f2bf(acc[mi][ni][1]);
                o.z = f2bf(acc[mi][ni][2]);
                o.w = f2bf(acc[mi][ni][3]);
                *(ushort4*)&Vt[((size_t)(b * NUM_HEADS + h) * DK + dk) * SEQ + s] = o;
            }
    } else { // ---- Q/K: fused RoPE ----
        unsigned short* Dst = (sec == 0) ? Qr : Kr;
#pragma unroll
        for (int ni = 0; ni < 4; ++ni) {
            int gn = n0 + wc + ni * 16 + mA;
            int d = gn & 1023, h = d >> 6, dk = d & 63;
            float invf = __expf(-(float)(dk & ~1) * (9.210340371976184f / 64.0f));
            float sgn = (dk & 1) ? 1.0f : -1.0f;
#pragma unroll
            for (int mi = 0; mi < 4; ++mi) {
#pragma unroll
                for (int r = 0; r < 4; ++r) {
                    int gm = m0 + wr + mi * 16 + quad * 4 + r;
                    int b = gm >> 11, s = gm & 2047;
                    float sn, cs;
                    __sincosf((float)s * invf, &sn, &cs);
                    float val = acc[mi][ni][r];
                    float par = __shfl_xor(val, 1, 64); // partner d^1 = lane^1
                    float outv = val * cs + sgn * par * sn;
                    Dst[((size_t)(b * NUM_HEADS + h) * SEQ + s) * DK + dk] = f2bf(outv);
                }
            }
        }
    }
}

// ---------------- GEMM 128 x TN, BK=64: C = A * B^T (out-projection) -------
template <int TN, int OUT_BF16>
__global__ __launch_bounds__(256) void gemm_tile(
    const unsigned short* __restrict__ A, const unsigned short* __restrict__ B,
    void* __restrict__ Cout, int M, int N, int K) {
    __shared__ unsigned short As[128 * 64];
    __shared__ unsigned short Bs[TN * 64];
    const int m0 = blockIdx.y * 128, n0 = blockIdx.x * TN;
    const int t = threadIdx.x;
    const int lane = t & 63, wave = t >> 6;
    const int mA = lane & 15, quad = lane >> 4;
    constexpr int MI = (TN == 128) ? 4 : 2;
    constexpr int NI = 4;
    const int wr = (TN == 128) ? (wave >> 1) * 64 : wave * 32;
    const int wc = (TN == 128) ? (wave & 1) * 64 : 0;

    f32x4 acc[MI][NI] = {};
    for (int k0 = 0; k0 < K; k0 += 64) {
#pragma unroll
        for (int i = 0; i < 4; ++i) {
            int ch = i * 256 + t;
            int r = ch >> 3, b = (ch & 7) ^ (r & 7);
            async16(A + (size_t)(m0 + r) * K + k0 + b * 8, (char*)As + ch * 16);
        }
#pragma unroll
        for (int i = 0; i < TN / 32; ++i) {
            int ch = i * 256 + t;
            int r = ch >> 3, b = (ch & 7) ^ (r & 7);
            async16(B + (size_t)(n0 + r) * K + k0 + b * 8, (char*)Bs + ch * 16);
        }
        __syncthreads();
#pragma unroll
        for (int kk = 0; kk < 2; ++kk) {
            bf16x8 af[MI], bfr[NI];
#pragma unroll
            for (int mi = 0; mi < MI; ++mi) {
                int rr = wr + mi * 16 + mA;
                af[mi] = *(const bf16x8*)&As[SWZ64(rr, kk * 4 + quad)];
            }
#pragma unroll
            for (int ni = 0; ni < NI; ++ni) {
                int rr = wc + ni * 16 + mA;
                bfr[ni] = *(const bf16x8*)&Bs[SWZ64(rr, kk * 4 + quad)];
            }
#pragma unroll
            for (int mi = 0; mi < MI; ++mi)
#pragma unroll
                for (int ni = 0; ni < NI; ++ni)
                    acc[mi][ni] = __builtin_amdgcn_mfma_f32_16x16x32_bf16(
                        af[mi], bfr[ni], acc[mi][ni], 0, 0, 0);
        }
        __syncthreads();
    }
#pragma unroll
    for (int mi = 0; mi < MI; ++mi)
#pragma unroll
        for (int ni = 0; ni < NI; ++ni)
#pragma unroll
            for (int r = 0; r < 4; ++r) {
                int gm = m0 + wr + mi * 16 + quad * 4 + r;
                int gn = n0 + wc + ni * 16 + mA;
                if (OUT_BF16)
                    ((unsigned short*)Cout)[(size_t)gm * N + gn] = f2bf(acc[mi][ni][r]);
                else
                    ((float*)Cout)[(size_t)gm * N + gn] = acc[mi][ni][r];
            }
}

// ---------------- Flash attention v6 (reverted from v7): LDS-staged KV -----
// 256 thr / 4 waves; block = 64 q rows of one (b,h). KV 64-tiles staged via
// global_load_lds shared by all 4 waves, double-buffered. LDS 40960 B ->
// 4 blocks/CU. Static-max softmax (offset cancels in P V / P 1).
__global__ __launch_bounds__(256, 4) void flash_attn6(
    const unsigned short* __restrict__ Qr, const unsigned short* __restrict__ Kr,
    const unsigned short* __restrict__ Vt, unsigned short* __restrict__ Att) {
    __shared__ unsigned short Ks[2][64 * 64]; // 16 KB (front reused for Lw)
    __shared__ unsigned short Vs[2][64 * 64]; // 16 KB
    __shared__ unsigned short Ps[4][16 * 64]; // 8 KB, XOR-swizzled rows
    const int bh = blockIdx.x;
    const int qt = 31 - (int)blockIdx.y; // LPT: longest first
    const int t = threadIdx.x;
    const int lane = t & 63, wave = t >> 6;
    const int mA = lane & 15, quad = lane >> 4;
    const int qr0 = qt * 64 + wave * 16;
    const size_t qkbase = (size_t)bh * SEQ * DK;
    const unsigned short* Kg = Kr + qkbase;
    const unsigned short* Vg = Vt + (size_t)bh * DK * SEQ;

    // Q fragments pre-scaled by 1/sqrt(dk)*log2e (base-2 softmax domain)
    bf16x8 aq[2];
#pragma unroll
    for (int c = 0; c < 2; ++c) {
        bf16x8 raw = *(const bf16x8*)&Qr[qkbase + (size_t)(qr0 + mA) * DK + c * 32 + quad * 8];
        bf16x8 s;
#pragma unroll
        for (int j = 0; j < 8; ++j)
            s[j] = (short)f2bf(bf2f((unsigned short)raw[j]) * (0.125f * LOG2E));
        aq[c] = s;
    }

    f32x4 accT[4] = {}; // O^T: row = outdim_local, col = q_local
    float lsum[4] = {};

    // stage tile 0 into buffer 0
#pragma unroll
    for (int i = 0; i < 2; ++i) {
        int ch = i * 256 + t;
        int row = ch >> 3, sb = (ch & 7) ^ (row & 7);
        async16(Kg + (size_t)row * DK + sb * 8, (char*)Ks[0] + ch * 16);
        async16(Vg + (size_t)row * SEQ + sb * 8, (char*)Vs[0] + ch * 16);
    }

    for (int jt = 0; jt <= qt; ++jt) {
        __syncthreads(); // stage(jt) visible; compute(jt-1) done
        const int cur = jt & 1;
        if (jt < qt) { // prefetch next tile (overlaps compute)
            const int j1 = (jt + 1) * 64;
#pragma unroll
            for (int i = 0; i < 2; ++i) {
                int ch = i * 256 + t;
                int row = ch >> 3, sb = (ch & 7) ^ (row & 7);
                async16(Kg + (size_t)(j1 + row) * DK + sb * 8, (char*)Ks[cur ^ 1] + ch * 16);
                async16(Vg + (size_t)row * SEQ + j1 + sb * 8, (char*)Vs[cur ^ 1] + ch * 16);
            }
        }
        const int j0 = jt * 64;
        const unsigned short* Kt = Ks[cur];
        const unsigned short* Vtile = Vs[cur];
        unsigned short* Pw = Ps[wave];

        // ---- QK^T: 16x64 scores (base-2 domain) ----
        f32x4 sc[4] = {};
#pragma unroll
        for (int js = 0; js < 4; ++js) {
            int row = js * 16 + mA;
            bf16x8 b0 = *(const bf16x8*)&Kt[SWZ64(row, quad)];
            bf16x8 b1 = *(const bf16x8*)&Kt[SWZ64(row, quad + 4)];
            sc[js] = __builtin_amdgcn_mfma_f32_16x16x32_bf16(aq[0], b0, sc[js], 0, 0, 0);
            sc[js] = __builtin_amdgcn_mfma_f32_16x16x32_bf16(aq[1], b1, sc[js], 0, 0, 0);
        }
        if (jt == qt) { // diagonal causal mask
#pragma unroll
            for (int js = 0; js < 4; ++js) {
                int gcol = j0 + js * 16 + mA;
#pragma unroll
                for (int r = 0; r < 4; ++r)
                    if (gcol > qr0 + quad * 4 + r) sc[js][r] = -1e30f;
            }
        }

        // ---- p = exp2(s - FIXM); P into swizzled per-wave LDS ----
#pragma unroll
        for (int js = 0; js < 4; ++js)
#pragma unroll
            for (int r = 0; r < 4; ++r) {
                float p = __builtin_amdgcn_exp2f(sc[js][r] - FIXM);
                lsum[r] += p;
                int q = quad * 4 + r;
                Pw[SWZ64(q, js * 2 + (mA >> 3)) + (mA & 7)] = f2bf_trunc(p);
            }
        bf16x8 ap0 = *(const bf16x8*)&Pw[SWZ64(mA, quad)];
        bf16x8 ap1 = *(const bf16x8*)&Pw[SWZ64(mA, quad + 4)];
#pragma unroll
        for (int tn = 0; tn < 4; ++tn) { // A=V, B=P -> O^T
            int row = tn * 16 + mA;
            bf16x8 bv0 = *(const bf16x8*)&Vtile[SWZ64(row, quad)];
            bf16x8 bv1 = *(const bf16x8*)&Vtile[SWZ64(row, quad + 4)];
            accT[tn] = __builtin_amdgcn_mfma_f32_16x16x32_bf16(bv0, ap0, accT[tn], 0, 0, 0);
            accT[tn] = __builtin_amdgcn_mfma_f32_16x16x32_bf16(bv1, ap1, accT[tn], 0, 0, 0);
        }
    }

    // ---- epilogue: reduce row sums across mA, broadcast via dead Ks ----
#pragma unroll
    for (int r = 0; r < 4; ++r)
#pragma unroll
        for (int off = 1; off < 16; off <<= 1)
            lsum[r] += __shfl_xor(lsum[r], off, 64);
    __syncthreads(); // all waves done with Ks
    float* LL = (float*)Ks;
    if (mA == 0)
#pragma unroll
        for (int r = 0; r < 4; ++r) LL[wave * 16 + quad * 4 + r] = lsum[r];
    __syncthreads();
    const float rl = 1.0f / LL[wave * 16 + mA]; // row sum for q = qr0 + mA

    const int b = bh >> 4, h = bh & 15;
#pragma unroll
    for (int tn = 0; tn < 4; ++tn) {
        ushort4 o;
        o.x = f2bf(accT[tn][0] * rl);
        o.y = f2bf(accT[tn][1] * rl);
        o.z = f2bf(accT[tn][2] * rl);
        o.w = f2bf(accT[tn][3] * rl);
        *(ushort4*)&Att[(size_t)(b * SEQ + qr0 + mA) * D_MODEL + h * DK + tn * 16 + quad * 4] = o;
    }
}

extern "C" void kernel_launch(void* const* d_in, const int* in_sizes, int n_in,
                              void* d_out, int out_size, void* d_ws, size_t ws_size,
                              hipStream_t stream) {
    const float* X = (const float*)d_in[0];
    const float* Wq = (const float*)d_in[1];
    const float* Wk = (const float*)d_in[2];
    const float* Wv = (const float*)d_in[3];
    const float* Wo = (const float*)d_in[4];

    char* ws = (char*)d_ws;
    // layout (MiB): Xb 0-8 | Wqkvb 8-14 | Wob 14-16 | Qr 16-24 | Kr 24-32 |
    //               Vt 32-40 | Att 40-48.  (Qr NOT aliased with Xb: the fused
    //               QKV GEMM writes Qr while other blocks still read Xb.)
    unsigned short* Xb    = (unsigned short*)(ws + 0);
    unsigned short* Wqkvb = (unsigned short*)(ws + (8u << 20));
    unsigned short* Wob   = (unsigned short*)(ws + (14u << 20));
    unsigned short* Qr    = (unsigned short*)(ws + (16u << 20));
    unsigned short* Kr    = (unsigned short*)(ws + (24u << 20));
    unsigned short* Vt    = (unsigned short*)(ws + (32u << 20));
    unsigned short* Att   = (unsigned short*)(ws + (40u << 20));

    cast_all<<<8192, 256, 0, stream>>>((const float4*)X, (const float4*)Wq,
                                       (const float4*)Wk, (const float4*)Wv,
                                       (const float4*)Wo, (ushort4*)Xb,
                                       (ushort4*)Wqkvb, (ushort4*)Wob);

    // fused QKV projection + RoPE + V-transpose (no QKVraw round trip)
    gemm_qkv_rope<<<dim3(3072 / 128, MROWS / 128), 256, 0, stream>>>(
        Xb, Wqkvb, Qr, Kr, Vt);

    flash_attn6<<<dim3(BATCH * NUM_HEADS, 32), 256, 0, stream>>>(Qr, Kr, Vt, Att);

    // output projection (fp32 out), 128x64 tiles for 2 blocks/CU
    gemm_tile<64, 0><<<dim3(D_MODEL / 64, MROWS / 128), 256, 0, stream>>>(
        Att, Wob, d_out, MROWS, D_MODEL, D_MODEL);
}